// Round 6
// baseline (113.518 us; speedup 1.0000x reference)
//
#include <hip/hip_runtime.h>
#include <stdint.h>

typedef unsigned long long u64;
typedef unsigned int u32;
typedef float f2 __attribute__((ext_vector_type(2)));

// ---- cross-lane helpers ----
__device__ __forceinline__ float dpp_shr1_f(float v, int fill_bits) {
  // within each 16-lane row: lane i <- lane i-1; row-lead takes fill
  return __int_as_float(__builtin_amdgcn_update_dpp(
      fill_bits, __float_as_int(v), 0x111 /*row_shr:1*/, 0xF, 0xF, false));
}
__device__ __forceinline__ int dpp_shr1_i(int v) {
  return __builtin_amdgcn_update_dpp(0, v, 0x111, 0xF, 0xF, false);
}
__device__ __forceinline__ float rdlane_f(float v, int lane) {
  return __int_as_float(__builtin_amdgcn_readlane(__float_as_int(v), lane));
}

// pack point pairs (n, n+32) of each 64-pt chunk:
// rec0 = {-2x0,-2x1,-2y0,-2y1}, rec1 = {-2z0,-2z1, pn0, pn1}
__global__ void prep_pack2(const float* __restrict__ pc, float4* __restrict__ pp,
                           int B, int N) {
  int r = blockIdx.x * blockDim.x + threadIdx.x;  // record id
  int H = N >> 1;
  if (r >= B * H) return;
  int b = r / H;
  int j = r - b * H;
  int k = j >> 5, t = j & 31;
  int n0 = (k << 6) + t, n1 = n0 + 32;
  const float* p = pc + (size_t)b * 3 * N;
  float x0 = p[n0], x1 = p[n1];
  float y0 = p[N + n0], y1 = p[N + n1];
  float z0 = p[2 * N + n0], z1 = p[2 * N + n1];
  float pn0 = __fadd_rn(__fadd_rn(__fmul_rn(x0, x0), __fmul_rn(y0, y0)),
                        __fmul_rn(z0, z0));
  float pn1 = __fadd_rn(__fadd_rn(__fmul_rn(x1, x1), __fmul_rn(y1, y1)),
                        __fmul_rn(z1, z1));
  pp[2 * r] = make_float4(__fmul_rn(x0, -2.0f), __fmul_rn(x1, -2.0f),
                          __fmul_rn(y0, -2.0f), __fmul_rn(y1, -2.0f));
  pp[2 * r + 1] = make_float4(__fmul_rn(z0, -2.0f), __fmul_rn(z1, -2.0f),
                              pn0, pn1);
}

template <bool PACKED>
__global__ __launch_bounds__(256, 8) void knn6(
    const float* __restrict__ pc,    // (B,3,N)
    const float* __restrict__ qc,    // (B,3,M)
    const float* __restrict__ temp,  // scalar
    const float4* __restrict__ pp,   // packed pair records
    float* __restrict__ out,         // (B,3,M)
    int B, int N, int M) {
#pragma clang fp contract(off)
  const float INF = __int_as_float(0x7f800000);
  const int NINF_BITS = (int)0xff800000;

  int tid = threadIdx.x;
  int lane = tid & 63;
  int grp = lane >> 5;   // 0: lanes 0-31 = query A; 1: lanes 32-63 = query B
  int sub = lane & 31;
  int qid = blockIdx.x * 8 + (tid >> 5);
  int b = qid >> 11;     // M = 2048
  int q = qid & 2047;

  float qx = qc[(b * 3 + 0) * M + q];
  float qy = qc[(b * 3 + 1) * M + q];
  float qz = qc[(b * 3 + 2) * M + q];
  float qn = __fadd_rn(__fadd_rn(__fmul_rn(qx, qx), __fmul_rn(qy, qy)),
                       __fmul_rn(qz, qz));
  f2 qx2 = {qx, qx}, qy2 = {qy, qy}, qz2 = {qz, qz}, qn2 = {qn, qn};

  // distributed top-16: lane (l&15) holds entry (l&15), ascending.
  // rows 0,1 mirror query A; rows 2,3 mirror query B.
  float val = INF;
  int idx = 0;
  float thresh = INF;

  const float* __restrict__ pcb = pc + (size_t)b * 3 * N;

  // merged A/B sorted-insert: one candidate from each query per round
  // (branchless round body; serial dep only through val/idx)
  auto insert32 = [&](u32 mA, u32 mB, float dv, int g) {
    while (mA | mB) {
      int sA = __ffs(mA) - 1;     // ascending index = top_k tie-break
      int sB = __ffs(mB) - 1;
      int lA = (sA < 0) ? 0 : sA;
      int lB = (sB < 0) ? 32 : (sB + 32);
      float cA = rdlane_f(dv, lA);
      float cB = rdlane_f(dv, lB);
      if (sA < 0) cA = INF;
      if (sB < 0) cB = INF;
      int ciA = g + lA;
      int ciB = g + (lB - 32);
      float cv = grp ? cB : cA;
      int ci = grp ? ciB : ciA;
      float pvv = dpp_shr1_f(val, NINF_BITS);
      int piv = dpp_shr1_i(idx);
      bool p = cv < val;          // strict < keeps stability
      bool p2 = cv < pvv;
      val = p ? (p2 ? pvv : cv) : val;
      idx = p ? (p2 ? piv : ci) : idx;
      if (mA) mA &= mA - 1;
      if (mB) mB &= mB - 1;
    }
  };

  auto body = [&](float4 c0, float4 c1, int g) {
    f2 px = {c0.x, c0.y}, py = {c0.z, c0.w};
    f2 pz = {c1.x, c1.y}, pw = {c1.z, c1.w};
    // d2 = (qn+pn) + (qx*(-2px)+qy*(-2py)+qz*(-2pz))  == reference bit-exactly
    f2 s1 = qx2 * px;
    f2 s2 = qy2 * py;
    f2 s3 = qz2 * pz;
    f2 t = (s1 + s2) + s3;
    f2 d2 = (qn2 + pw) + t;
    u64 m0 = __ballot(d2.x < thresh);  // points g   .. g+31
    u64 m1 = __ballot(d2.y < thresh);  // points g+32.. g+63
    if (m0 | m1) {
      if (m0) insert32((u32)m0, (u32)(m0 >> 32), d2.x, g);
      if (m1) insert32((u32)m1, (u32)(m1 >> 32), d2.y, g + 32);
      // refresh own group's threshold = entry 15; short VALU chain (no LDS)
      float tA = rdlane_f(val, 15);
      float tB = rdlane_f(val, 47);
      thresh = grp ? tB : tA;
    }
  };

  if (PACKED) {
    // group = 128 points = 2 chunks = 4 float4/lane; byte stride 2048.
    // loads use immediate offsets 0,16,1024,1040 off a per-lane cursor.
    const char* base = (const char*)(pp + (size_t)b * N) + sub * 32;
    const float4* g0 = (const float4*)base;
    float4 a0 = g0[0], a1 = g0[1], a2 = g0[64], a3 = g0[65];
#pragma unroll 1
    for (int g = 0; g < 64; g += 2) {
      const float4* g1 = (const float4*)(base + (g + 1) * 2048);
      float4 b0 = g1[0], b1 = g1[1], b2 = g1[64], b3 = g1[65];
      body(a0, a1, g * 128);
      body(a2, a3, g * 128 + 64);
      const float4* g2 = (const float4*)(base + ((g + 2) & 63) * 2048);
      a0 = g2[0]; a1 = g2[1]; a2 = g2[64]; a3 = g2[65];  // wrap harmless
      body(b0, b1, (g + 1) * 128);
      body(b2, b3, (g + 1) * 128 + 64);
    }
  } else {
#pragma unroll 1
    for (int g = 0; g < N; g += 64) {
      int n0 = g + sub, n1 = g + sub + 32;
      float x0 = pcb[n0], x1 = pcb[n1];
      float y0 = pcb[N + n0], y1 = pcb[N + n1];
      float z0 = pcb[2 * N + n0], z1 = pcb[2 * N + n1];
      float pn0 = __fadd_rn(__fadd_rn(__fmul_rn(x0, x0), __fmul_rn(y0, y0)),
                            __fmul_rn(z0, z0));
      float pn1 = __fadd_rn(__fadd_rn(__fmul_rn(x1, x1), __fmul_rn(y1, y1)),
                            __fmul_rn(z1, z1));
      float4 c0 = make_float4(__fmul_rn(x0, -2.0f), __fmul_rn(x1, -2.0f),
                              __fmul_rn(y0, -2.0f), __fmul_rn(y1, -2.0f));
      float4 c1 = make_float4(__fmul_rn(z0, -2.0f), __fmul_rn(z1, -2.0f),
                              pn0, pn1);
      body(c0, c1, g);
    }
  }

  // ---- finisher (np-faithful): lane (l&15) owns entry (l&15) ----
  float Tv = temp[0];
  float sigma = fmaxf(__fmul_rn(Tv, Tv), 1e-4f);
  float sp = __fadd_rn(sigma, 1e-8f);
  int n = idx;
  float px = pcb[n], py = pcb[N + n], pz = pcb[2 * N + n];
  float dx = __fsub_rn(px, qx), dy = __fsub_rn(py, qy), dz = __fsub_rn(pz, qz);
  float d2w = __fadd_rn(__fadd_rn(__fmul_rn(dx, dx), __fmul_rn(dy, dy)),
                        __fmul_rn(dz, dz));
  float a = -__fdiv_rn(d2w, sp);                     // -dist
  float m = grp ? rdlane_f(a, 32) : rdlane_f(a, 0);  // max = entry 0 (sorted)
  float e = expf(__fsub_rn(a, m));
  float Z = e;
#pragma unroll
  for (int d = 1; d < 16; d <<= 1) Z += __shfl_xor(Z, d, 16);
  float w = __fdiv_rn(e, Z);                         // normalized weight
  float sx = __fmul_rn(px, w), sy = __fmul_rn(py, w), sz = __fmul_rn(pz, w);
#pragma unroll
  for (int d = 1; d < 16; d <<= 1) {
    sx += __shfl_xor(sx, d, 16);
    sy += __shfl_xor(sy, d, 16);
    sz += __shfl_xor(sz, d, 16);
  }
  if ((lane & 31) < 3) {
    int c = lane & 31;
    float r = (c == 0) ? sx : ((c == 1) ? sy : sz);
    out[(b * 3 + c) * M + q] = r;
  }
}

extern "C" void kernel_launch(void* const* d_in, const int* in_sizes, int n_in,
                              void* d_out, int out_size, void* d_ws, size_t ws_size,
                              hipStream_t stream) {
  const int B = 8, N = 8192, M = 2048;
  const float* pc = (const float*)d_in[0];
  const float* qc = (const float*)d_in[1];
  const float* temp = (const float*)d_in[2];
  float* out = (float*)d_out;

  size_t packBytes = (size_t)B * N * 16;  // B*N/2 records * 32B
  bool packed = (ws_size >= packBytes) && (d_ws != nullptr);

  int nblocks = (B * M) / 8;  // 8 queries / 256-thread block (2 per wave)
  if (packed) {
    int R = B * (N >> 1);
    prep_pack2<<<dim3((R + 255) / 256), dim3(256), 0, stream>>>(
        pc, (float4*)d_ws, B, N);
    knn6<true><<<dim3(nblocks), dim3(256), 0, stream>>>(
        pc, qc, temp, (const float4*)d_ws, out, B, N, M);
  } else {
    knn6<false><<<dim3(nblocks), dim3(256), 0, stream>>>(
        pc, qc, temp, nullptr, out, B, N, M);
  }
}

// Round 7
// 97.608 us; speedup vs baseline: 1.1630x; 1.1630x over previous
//
#include <hip/hip_runtime.h>
#include <stdint.h>

typedef unsigned long long u64;
typedef unsigned int u32;

// ---- cross-lane helpers ----
__device__ __forceinline__ float dpp_shr1_f(float v, int fill_bits) {
  // within each 16-lane row: lane i <- lane i-1; row-lead takes fill
  return __int_as_float(__builtin_amdgcn_update_dpp(
      fill_bits, __float_as_int(v), 0x111 /*row_shr:1*/, 0xF, 0xF, false));
}
__device__ __forceinline__ int dpp_shr1_i(int v) {
  return __builtin_amdgcn_update_dpp(0, v, 0x111, 0xF, 0xF, false);
}
__device__ __forceinline__ float rdlane_f(float v, int lane) {
  return __int_as_float(__builtin_amdgcn_readlane(__float_as_int(v), lane));
}

// R3-verified pack (absmax 0.0): (-2x, -2y, -2z, |p|^2); x(-2) is exact so
// q·(-2p) == -2*inner bit-exactly, pn in numpy order.
__global__ void prep_pack(const float* __restrict__ pc, float4* __restrict__ pp,
                          int B, int N) {
  int i = blockIdx.x * blockDim.x + threadIdx.x;
  if (i >= B * N) return;
  int b = i / N, n = i - b * N;
  float x = pc[(b * 3 + 0) * N + n];
  float y = pc[(b * 3 + 1) * N + n];
  float z = pc[(b * 3 + 2) * N + n];
  float pn = __fadd_rn(__fadd_rn(__fmul_rn(x, x), __fmul_rn(y, y)),
                       __fmul_rn(z, z));
  pp[i] = make_float4(__fmul_rn(x, -2.0f), __fmul_rn(y, -2.0f),
                      __fmul_rn(z, -2.0f), pn);
}

template <bool PACKED>
__global__ __launch_bounds__(256, 8) void knn7(
    const float* __restrict__ pc,    // (B,3,N)
    const float* __restrict__ qc,    // (B,3,M)
    const float* __restrict__ temp,  // scalar
    const float4* __restrict__ pp,   // packed (B,N): -2x,-2y,-2z,|p|^2
    float* __restrict__ out,         // (B,3,M)
    int B, int N, int M) {
#pragma clang fp contract(off)
  const float INF = __int_as_float(0x7f800000);
  const int NINF_BITS = (int)0xff800000;

  int tid = threadIdx.x;
  int lane = tid & 63;
  int qid = blockIdx.x * 4 + (tid >> 6);  // ONE query per wave
  int b = qid >> 11;                      // M = 2048
  int q = qid & 2047;

  float qx = qc[(b * 3 + 0) * M + q];
  float qy = qc[(b * 3 + 1) * M + q];
  float qz = qc[(b * 3 + 2) * M + q];
  float qn = __fadd_rn(__fadd_rn(__fmul_rn(qx, qx), __fmul_rn(qy, qy)),
                       __fmul_rn(qz, qz));

  // distributed top-16: lane (l&15) holds entry (l&15), ascending;
  // all four 16-lane rows mirror the same list (updates are wave-uniform).
  float val = INF;
  int idx = 0;
  float thresh = INF;

  const float* __restrict__ pcb = pc + (size_t)b * 3 * N;

  // per-64-pt-batch: distance (6 VALU) + ballot; serial insert only on hits
  auto body = [&](float4 c, int g) {
    // d2 = (qn+pn) + (qx*(-2px)+qy*(-2py)+qz*(-2pz))  == reference bit-exactly
    float s1 = __fmul_rn(qx, c.x);
    float s2 = __fmul_rn(qy, c.y);
    float s3 = __fmul_rn(qz, c.z);
    float t = __fadd_rn(__fadd_rn(s1, s2), s3);
    float d2 = __fadd_rn(__fadd_rn(qn, c.w), t);
    u64 m = __ballot(d2 < thresh);
    if (m) {
      do {
        int s = __ffsll((long long)m) - 1;  // ascending idx = top_k tie-break
        m &= m - 1;
        float cv = rdlane_f(d2, s);         // uniform scalar candidate
        int ci = g + s;
        float pvv = dpp_shr1_f(val, NINF_BITS);
        int piv = dpp_shr1_i(idx);
        bool p = cv < val;                  // strict < keeps stability
        bool p2 = cv < pvv;
        val = p ? (p2 ? pvv : cv) : val;
        idx = p ? (p2 ? piv : ci) : idx;
      } while (m);
      thresh = rdlane_f(val, 15);           // 16th-best -> SGPR
    }
  };

  if (PACKED) {
    const float4* __restrict__ pb = pp + (size_t)b * N + lane;
    float4 c0 = pb[0], c1 = pb[64];
#pragma unroll 1
    for (int g = 0; g < N; g += 128) {
      int gn = (g + 128) & (N - 1);         // wrap prefetch harmless
      float4 n0 = pb[gn], n1 = pb[gn + 64];
      body(c0, g);
      body(c1, g + 64);
      c0 = n0; c1 = n1;
    }
  } else {
#pragma unroll 1
    for (int g = 0; g < N; g += 64) {
      int n = g + lane;
      float x = pcb[n], y = pcb[N + n], z = pcb[2 * N + n];
      float pn = __fadd_rn(__fadd_rn(__fmul_rn(x, x), __fmul_rn(y, y)),
                           __fmul_rn(z, z));
      float4 c = make_float4(__fmul_rn(x, -2.0f), __fmul_rn(y, -2.0f),
                             __fmul_rn(z, -2.0f), pn);
      body(c, g);
    }
  }

  // ---- finisher (np-faithful; R3 heritage): lane (l&15) owns entry (l&15) ----
  float Tv = temp[0];
  float sigma = fmaxf(__fmul_rn(Tv, Tv), 1e-4f);
  float sp = __fadd_rn(sigma, 1e-8f);
  int n = idx;
  float px = pcb[n], py = pcb[N + n], pz = pcb[2 * N + n];
  float dx = __fsub_rn(px, qx), dy = __fsub_rn(py, qy), dz = __fsub_rn(pz, qz);
  float d2w = __fadd_rn(__fadd_rn(__fmul_rn(dx, dx), __fmul_rn(dy, dy)),
                        __fmul_rn(dz, dz));
  float a = -__fdiv_rn(d2w, sp);   // -dist; softmax shift-invariant, m ~ max
  float m = rdlane_f(a, 0);        // entry 0 = nearest (sorted ascending)
  float e = expf(__fsub_rn(a, m));
  float Z = e;
#pragma unroll
  for (int d = 1; d < 16; d <<= 1) Z += __shfl_xor(Z, d, 16);
  float w = __fdiv_rn(e, Z);       // normalized weight
  float sx = __fmul_rn(px, w), sy = __fmul_rn(py, w), sz = __fmul_rn(pz, w);
#pragma unroll
  for (int d = 1; d < 16; d <<= 1) {
    sx += __shfl_xor(sx, d, 16);
    sy += __shfl_xor(sy, d, 16);
    sz += __shfl_xor(sz, d, 16);
  }
  if (lane < 3) {
    float r = (lane == 0) ? sx : ((lane == 1) ? sy : sz);
    out[(b * 3 + lane) * M + q] = r;
  }
}

extern "C" void kernel_launch(void* const* d_in, const int* in_sizes, int n_in,
                              void* d_out, int out_size, void* d_ws, size_t ws_size,
                              hipStream_t stream) {
  const int B = 8, N = 8192, M = 2048;
  const float* pc = (const float*)d_in[0];
  const float* qc = (const float*)d_in[1];
  const float* temp = (const float*)d_in[2];
  float* out = (float*)d_out;

  size_t packBytes = (size_t)B * N * sizeof(float4);
  bool packed = (ws_size >= packBytes) && (d_ws != nullptr);

  int nblocks = (B * M) / 4;  // 4 queries / 256-thread block (1 per wave)
  if (packed) {
    prep_pack<<<dim3((B * N + 255) / 256), dim3(256), 0, stream>>>(
        pc, (float4*)d_ws, B, N);
    knn7<true><<<dim3(nblocks), dim3(256), 0, stream>>>(
        pc, qc, temp, (const float4*)d_ws, out, B, N, M);
  } else {
    knn7<false><<<dim3(nblocks), dim3(256), 0, stream>>>(
        pc, qc, temp, nullptr, out, B, N, M);
  }
}

// Round 8
// 93.764 us; speedup vs baseline: 1.2107x; 1.0410x over previous
//
#include <hip/hip_runtime.h>
#include <stdint.h>

typedef unsigned long long u64;
typedef unsigned int u32;
typedef float f2 __attribute__((ext_vector_type(2)));

// ---- cross-lane helpers ----
__device__ __forceinline__ float dpp_shr1_f(float v, int fill_bits) {
  // within each 16-lane row: lane i <- lane i-1; row-lead takes fill
  return __int_as_float(__builtin_amdgcn_update_dpp(
      fill_bits, __float_as_int(v), 0x111 /*row_shr:1*/, 0xF, 0xF, false));
}
__device__ __forceinline__ int dpp_shr1_i(int v) {
  return __builtin_amdgcn_update_dpp(0, v, 0x111, 0xF, 0xF, false);
}
__device__ __forceinline__ float rdlane_f(float v, int lane) {
  return __int_as_float(__builtin_amdgcn_readlane(__float_as_int(v), lane));
}

// pair records for 128-pt chunks: pair (n0 = k*128+t, n1 = n0+64), t=0..63
// rec0 = {-2x0,-2x1,-2y0,-2y1}, rec1 = {-2z0,-2z1, pn0, pn1}
// x(-2) is exact so q*(-2p) == -2*inner bit-exactly; pn in numpy order.
__global__ void prep_pack2(const float* __restrict__ pc, float4* __restrict__ pp,
                           int B, int N) {
  int r = blockIdx.x * blockDim.x + threadIdx.x;  // pair id
  int H = N >> 1;
  if (r >= B * H) return;
  int b = r / H;
  int j = r - b * H;
  int k = j >> 6, t = j & 63;
  int n0 = (k << 7) + t, n1 = n0 + 64;
  const float* p = pc + (size_t)b * 3 * N;
  float x0 = p[n0], x1 = p[n1];
  float y0 = p[N + n0], y1 = p[N + n1];
  float z0 = p[2 * N + n0], z1 = p[2 * N + n1];
  float pn0 = __fadd_rn(__fadd_rn(__fmul_rn(x0, x0), __fmul_rn(y0, y0)),
                        __fmul_rn(z0, z0));
  float pn1 = __fadd_rn(__fadd_rn(__fmul_rn(x1, x1), __fmul_rn(y1, y1)),
                        __fmul_rn(z1, z1));
  pp[2 * r] = make_float4(__fmul_rn(x0, -2.0f), __fmul_rn(x1, -2.0f),
                          __fmul_rn(y0, -2.0f), __fmul_rn(y1, -2.0f));
  pp[2 * r + 1] = make_float4(__fmul_rn(z0, -2.0f), __fmul_rn(z1, -2.0f),
                              pn0, pn1);
}

template <bool PACKED>
__global__ __launch_bounds__(256, 8) void knn8(
    const float* __restrict__ pc,    // (B,3,N)
    const float* __restrict__ qc,    // (B,3,M)
    const float* __restrict__ temp,  // scalar
    const float4* __restrict__ pp,   // packed pair records
    float* __restrict__ out,         // (B,3,M)
    int B, int N, int M) {
#pragma clang fp contract(off)
  const float INF = __int_as_float(0x7f800000);
  const int NINF_BITS = (int)0xff800000;

  int tid = threadIdx.x;
  int lane = tid & 63;
  int qid = blockIdx.x * 4 + (tid >> 6);  // ONE query per wave
  int b = qid >> 11;                      // M = 2048
  int q = qid & 2047;

  float qx = qc[(b * 3 + 0) * M + q];
  float qy = qc[(b * 3 + 1) * M + q];
  float qz = qc[(b * 3 + 2) * M + q];
  float qn = __fadd_rn(__fadd_rn(__fmul_rn(qx, qx), __fmul_rn(qy, qy)),
                       __fmul_rn(qz, qz));
  f2 qx2 = {qx, qx}, qy2 = {qy, qy}, qz2 = {qz, qz}, qn2 = {qn, qn};

  // distributed top-16: lane (l&15) holds entry (l&15), ascending; all four
  // 16-lane rows mirror the same list (updates are wave-uniform).
  float val = INF;
  int idx = 0;
  float thresh = INF;

  const float* __restrict__ pcb = pc + (size_t)b * 3 * N;

  // serial sorted-insert of candidates in mask (bit s <-> point g+s, ascending)
  auto ins = [&](u64 m, float dv, int g) {
    do {
      int s = __ffsll((long long)m) - 1;  // ascending idx = top_k tie-break
      m &= m - 1;
      float cv = rdlane_f(dv, s);         // wave-uniform candidate (SGPR)
      int ci = g + s;                     // SALU
      float pvv = dpp_shr1_f(val, NINF_BITS);
      int piv = dpp_shr1_i(idx);
      bool p = cv < val;                  // strict < keeps stability
      bool p2 = cv < pvv;
      float nv = __builtin_amdgcn_fmed3f(val, pvv, cv);  // sorted-insert step
      idx = p ? (p2 ? piv : ci) : idx;
      val = nv;
    } while (m);
  };

  if (PACKED) {
    const float4* __restrict__ pb4 = pp + (size_t)b * N + (lane << 1);
#pragma unroll 1
    for (int k = 0; k < (N >> 7); ++k) {
      float4 c0 = pb4[(size_t)k << 7];
      float4 c1 = pb4[((size_t)k << 7) + 1];
      // d2 = (qn+pn) + (qx*(-2px)+qy*(-2py)+qz*(-2pz)) == reference bit-exact
      f2 px = {c0.x, c0.y}, py = {c0.z, c0.w};
      f2 pz = {c1.x, c1.y}, pw = {c1.z, c1.w};
      f2 s1 = qx2 * px;
      f2 s2 = qy2 * py;
      f2 s3 = qz2 * pz;
      f2 t = (s1 + s2) + s3;
      f2 d2 = (qn2 + pw) + t;
      int g = k << 7;
      u64 m0 = __ballot(d2.x < thresh);   // points g    .. g+63
      if (m0) {
        ins(m0, d2.x, g);
        thresh = rdlane_f(val, 15);       // fresh threshold before half 2
      }
      u64 m1 = __ballot(d2.y < thresh);   // points g+64 .. g+127
      if (m1) {
        ins(m1, d2.y, g + 64);
        thresh = rdlane_f(val, 15);
      }
    }
  } else {
#pragma unroll 1
    for (int g = 0; g < N; g += 64) {
      int n = g + lane;
      float x = pcb[n], y = pcb[N + n], z = pcb[2 * N + n];
      float pn = __fadd_rn(__fadd_rn(__fmul_rn(x, x), __fmul_rn(y, y)),
                           __fmul_rn(z, z));
      float s1 = __fmul_rn(qx, __fmul_rn(x, -2.0f));
      float s2 = __fmul_rn(qy, __fmul_rn(y, -2.0f));
      float s3 = __fmul_rn(qz, __fmul_rn(z, -2.0f));
      float t = __fadd_rn(__fadd_rn(s1, s2), s3);
      float d2 = __fadd_rn(__fadd_rn(qn, pn), t);
      u64 m = __ballot(d2 < thresh);
      if (m) {
        ins(m, d2, g);
        thresh = rdlane_f(val, 15);
      }
    }
  }

  // ---- finisher (np-faithful): lane (l&15) owns entry (l&15) ----
  float Tv = temp[0];
  float sigma = fmaxf(__fmul_rn(Tv, Tv), 1e-4f);
  float sp = __fadd_rn(sigma, 1e-8f);
  int n = idx;
  float px = pcb[n], py = pcb[N + n], pz = pcb[2 * N + n];
  float dx = __fsub_rn(px, qx), dy = __fsub_rn(py, qy), dz = __fsub_rn(pz, qz);
  float d2w = __fadd_rn(__fadd_rn(__fmul_rn(dx, dx), __fmul_rn(dy, dy)),
                        __fmul_rn(dz, dz));
  float a = -__fdiv_rn(d2w, sp);   // -dist; softmax shift-invariant
  float m = rdlane_f(a, 0);        // entry 0 = nearest (sorted ascending)
  float e = expf(__fsub_rn(a, m));
  float Z = e;
#pragma unroll
  for (int d = 1; d < 16; d <<= 1) Z += __shfl_xor(Z, d, 16);
  float w = __fdiv_rn(e, Z);       // normalized weight
  float sx = __fmul_rn(px, w), sy = __fmul_rn(py, w), sz = __fmul_rn(pz, w);
#pragma unroll
  for (int d = 1; d < 16; d <<= 1) {
    sx += __shfl_xor(sx, d, 16);
    sy += __shfl_xor(sy, d, 16);
    sz += __shfl_xor(sz, d, 16);
  }
  if (lane < 3) {
    float r = (lane == 0) ? sx : ((lane == 1) ? sy : sz);
    out[(b * 3 + lane) * M + q] = r;
  }
}

extern "C" void kernel_launch(void* const* d_in, const int* in_sizes, int n_in,
                              void* d_out, int out_size, void* d_ws, size_t ws_size,
                              hipStream_t stream) {
  const int B = 8, N = 8192, M = 2048;
  const float* pc = (const float*)d_in[0];
  const float* qc = (const float*)d_in[1];
  const float* temp = (const float*)d_in[2];
  float* out = (float*)d_out;

  size_t packBytes = (size_t)B * N * 16;  // B*N/2 pairs * 32B
  bool packed = (ws_size >= packBytes) && (d_ws != nullptr);

  int nblocks = (B * M) / 4;  // 4 queries / 256-thread block (1 per wave)
  if (packed) {
    int R = B * (N >> 1);
    prep_pack2<<<dim3((R + 255) / 256), dim3(256), 0, stream>>>(
        pc, (float4*)d_ws, B, N);
    knn8<true><<<dim3(nblocks), dim3(256), 0, stream>>>(
        pc, qc, temp, (const float4*)d_ws, out, B, N, M);
  } else {
    knn8<false><<<dim3(nblocks), dim3(256), 0, stream>>>(
        pc, qc, temp, nullptr, out, B, N, M);
  }
}

// Round 9
// 84.570 us; speedup vs baseline: 1.3423x; 1.1087x over previous
//
#include <hip/hip_runtime.h>
#include <stdint.h>

typedef unsigned long long u64;
typedef unsigned int u32;
typedef float f2 __attribute__((ext_vector_type(2)));

// ---- cross-lane helpers ----
__device__ __forceinline__ float dpp_shr1_f(float v, int fill_bits) {
  // within each 16-lane row: lane i <- lane i-1; row-lead takes fill
  return __int_as_float(__builtin_amdgcn_update_dpp(
      fill_bits, __float_as_int(v), 0x111 /*row_shr:1*/, 0xF, 0xF, false));
}
__device__ __forceinline__ int dpp_shr1_i(int v) {
  return __builtin_amdgcn_update_dpp(0, v, 0x111, 0xF, 0xF, false);
}
__device__ __forceinline__ float rdlane_f(float v, int lane) {
  return __int_as_float(__builtin_amdgcn_readlane(__float_as_int(v), lane));
}
// order-preserving float-bits -> u32 (monotone over all floats incl. negatives)
__device__ __forceinline__ u32 fkey(u32 s) {
  return s ^ ((u32)((int)s >> 31) | 0x80000000u);
}

// pair records for 128-pt chunks: pair (n0 = k*128+t, n1 = n0+64), t=0..63
// rec0 = {-2x0,-2x1,-2y0,-2y1}, rec1 = {-2z0,-2z1, pn0, pn1}
// x(-2) is exact so q*(-2p) == -2*inner bit-exactly; pn in numpy order.
__global__ void prep_pack2(const float* __restrict__ pc, float4* __restrict__ pp,
                           int B, int N) {
  int r = blockIdx.x * blockDim.x + threadIdx.x;  // pair id
  int H = N >> 1;
  if (r >= B * H) return;
  int b = r / H;
  int j = r - b * H;
  int k = j >> 6, t = j & 63;
  int n0 = (k << 7) + t, n1 = n0 + 64;
  const float* p = pc + (size_t)b * 3 * N;
  float x0 = p[n0], x1 = p[n1];
  float y0 = p[N + n0], y1 = p[N + n1];
  float z0 = p[2 * N + n0], z1 = p[2 * N + n1];
  float pn0 = __fadd_rn(__fadd_rn(__fmul_rn(x0, x0), __fmul_rn(y0, y0)),
                        __fmul_rn(z0, z0));
  float pn1 = __fadd_rn(__fadd_rn(__fmul_rn(x1, x1), __fmul_rn(y1, y1)),
                        __fmul_rn(z1, z1));
  pp[2 * r] = make_float4(__fmul_rn(x0, -2.0f), __fmul_rn(x1, -2.0f),
                          __fmul_rn(y0, -2.0f), __fmul_rn(y1, -2.0f));
  pp[2 * r + 1] = make_float4(__fmul_rn(z0, -2.0f), __fmul_rn(z1, -2.0f),
                              pn0, pn1);
}

template <bool PACKED>
__global__ __launch_bounds__(256, 8) void knn9(
    const float* __restrict__ pc,    // (B,3,N)
    const float* __restrict__ qc,    // (B,3,M)
    const float* __restrict__ temp,  // scalar
    const float4* __restrict__ pp,   // packed pair records
    float* __restrict__ out,         // (B,3,M)
    int B, int N, int M) {
#pragma clang fp contract(off)
  const float INF = __int_as_float(0x7f800000);
  const int NINF_BITS = (int)0xff800000;

  int tid = threadIdx.x;
  int lane = tid & 63;
  int qid = blockIdx.x * 4 + (tid >> 6);  // ONE query per wave
  int b = qid >> 11;                      // M = 2048
  int q = qid & 2047;

  float qx = qc[(b * 3 + 0) * M + q];
  float qy = qc[(b * 3 + 1) * M + q];
  float qz = qc[(b * 3 + 2) * M + q];
  float qn = __fadd_rn(__fadd_rn(__fmul_rn(qx, qx), __fmul_rn(qy, qy)),
                       __fmul_rn(qz, qz));
  f2 qx2 = {qx, qx}, qy2 = {qy, qy}, qz2 = {qz, qz}, qn2 = {qn, qn};

  // distributed top-16: lane (l&15) holds entry (l&15), ascending; all four
  // 16-lane rows mirror the same list (updates are wave-uniform).
  float val = INF;
  int idx = 0;
  float thresh = INF;

  const float* __restrict__ pcb = pc + (size_t)b * 3 * N;

  // serial sorted-insert of candidates in mask (bit s <-> point g+s, ascending)
  auto ins = [&](u64 m, float dv, int g) {
    do {
      int s = __ffsll((long long)m) - 1;  // ascending idx = top_k tie-break
      m &= m - 1;
      float cv = rdlane_f(dv, s);         // wave-uniform candidate
      int ci = g + s;                     // SALU
      float pvv = dpp_shr1_f(val, NINF_BITS);
      int piv = dpp_shr1_i(idx);
      bool p = cv < val;                  // strict < keeps stability
      bool p2 = cv < pvv;
      float nv = __builtin_amdgcn_fmed3f(val, pvv, cv);  // sorted-insert step
      idx = p ? (p2 ? piv : ci) : idx;
      val = nv;
    } while (m);
  };

  auto dist = [&](float4 c0, float4 c1) -> f2 {
    // d2 = (qn+pn) + (qx*(-2px)+qy*(-2py)+qz*(-2pz)) == reference bit-exact
    f2 px = {c0.x, c0.y}, py = {c0.z, c0.w};
    f2 pz = {c1.x, c1.y}, pw = {c1.z, c1.w};
    f2 s1 = qx2 * px;
    f2 s2 = qy2 * py;
    f2 s3 = qz2 * pz;
    f2 t = (s1 + s2) + s3;
    return (qn2 + pw) + t;
  };

  if (PACKED) {
    const float4* __restrict__ pb4 = pp + (size_t)b * N + (lane << 1);
    float4 c0 = pb4[0], c1 = pb4[1];
    float4 n0f = pb4[128], n1f = pb4[129];  // chunk-1 prefetch in flight
    f2 d2 = dist(c0, c1);

    // ---- warmup: bitonic sort (d2.x, lane) over all 64 lanes ----
    // key = order-preserving distance bits | point index (exact tie-break).
    u64 key = ((u64)fkey(__float_as_uint(d2.x)) << 32) | (u32)lane;
#pragma unroll
    for (int k = 2; k <= 64; k <<= 1) {
#pragma unroll
      for (int j = k >> 1; j >= 1; j >>= 1) {
        u32 klo = (u32)key, khi = (u32)(key >> 32);
        u32 plo = (u32)__shfl_xor((int)klo, j);
        u32 phi = (u32)__shfl_xor((int)khi, j);
        u64 pkey = ((u64)phi << 32) | plo;
        bool keepMin = ((lane & j) == 0) == ((lane & k) == 0);
        bool lt = key < pkey;
        key = (lt == keepMin) ? key : pkey;
      }
    }
    {  // distribute sorted entries 0..15 to all four mirror rows
      int src = (lane & 15) << 2;
      u32 lo = (u32)__builtin_amdgcn_ds_bpermute(src, (int)(u32)key);
      u32 hi = (u32)__builtin_amdgcn_ds_bpermute(src, (int)(key >> 32));
      idx = (int)lo;
      val = __uint_as_float(hi ^ (((int)hi >= 0) ? 0xFFFFFFFFu : 0x80000000u));
      thresh = rdlane_f(val, 15);
    }
    {  // chunk 0, second half (points 64..127)
      u64 m1 = __ballot(d2.y < thresh);
      if (m1) {
        ins(m1, d2.y, 64);
        thresh = rdlane_f(val, 15);
      }
    }
    // ---- main loop, chunks 1..63, 1-chunk prefetch double-buffer ----
#pragma unroll 1
    for (int k = 1; k < 64; ++k) {
      c0 = n0f; c1 = n1f;
      int kn = (k + 1) & 63;                       // wrap prefetch harmless
      n0f = pb4[(size_t)kn << 7];
      n1f = pb4[((size_t)kn << 7) + 1];
      f2 dd = dist(c0, c1);
      int g = k << 7;
      u64 m0 = __ballot(dd.x < thresh);            // points g    .. g+63
      if (m0) {
        ins(m0, dd.x, g);
        thresh = rdlane_f(val, 15);
      }
      u64 m1 = __ballot(dd.y < thresh);            // points g+64 .. g+127
      if (m1) {
        ins(m1, dd.y, g + 64);
        thresh = rdlane_f(val, 15);
      }
    }
  } else {
#pragma unroll 1
    for (int g = 0; g < N; g += 64) {
      int n = g + lane;
      float x = pcb[n], y = pcb[N + n], z = pcb[2 * N + n];
      float pn = __fadd_rn(__fadd_rn(__fmul_rn(x, x), __fmul_rn(y, y)),
                           __fmul_rn(z, z));
      float s1 = __fmul_rn(qx, __fmul_rn(x, -2.0f));
      float s2 = __fmul_rn(qy, __fmul_rn(y, -2.0f));
      float s3 = __fmul_rn(qz, __fmul_rn(z, -2.0f));
      float t = __fadd_rn(__fadd_rn(s1, s2), s3);
      float d2 = __fadd_rn(__fadd_rn(qn, pn), t);
      u64 m = __ballot(d2 < thresh);
      if (m) {
        ins(m, d2, g);
        thresh = rdlane_f(val, 15);
      }
    }
  }

  // ---- finisher (np-faithful): lane (l&15) owns entry (l&15) ----
  float Tv = temp[0];
  float sigma = fmaxf(__fmul_rn(Tv, Tv), 1e-4f);
  float sp = __fadd_rn(sigma, 1e-8f);
  int n = idx;
  float px = pcb[n], py = pcb[N + n], pz = pcb[2 * N + n];
  float dx = __fsub_rn(px, qx), dy = __fsub_rn(py, qy), dz = __fsub_rn(pz, qz);
  float d2w = __fadd_rn(__fadd_rn(__fmul_rn(dx, dx), __fmul_rn(dy, dy)),
                        __fmul_rn(dz, dz));
  float a = -__fdiv_rn(d2w, sp);   // -dist; softmax shift-invariant
  float m = rdlane_f(a, 0);        // entry 0 = nearest (sorted ascending)
  float e = expf(__fsub_rn(a, m));
  float Z = e;
#pragma unroll
  for (int d = 1; d < 16; d <<= 1) Z += __shfl_xor(Z, d, 16);
  float w = __fdiv_rn(e, Z);       // normalized weight
  float sx = __fmul_rn(px, w), sy = __fmul_rn(py, w), sz = __fmul_rn(pz, w);
#pragma unroll
  for (int d = 1; d < 16; d <<= 1) {
    sx += __shfl_xor(sx, d, 16);
    sy += __shfl_xor(sy, d, 16);
    sz += __shfl_xor(sz, d, 16);
  }
  if (lane < 3) {
    float r = (lane == 0) ? sx : ((lane == 1) ? sy : sz);
    out[(b * 3 + lane) * M + q] = r;
  }
}

extern "C" void kernel_launch(void* const* d_in, const int* in_sizes, int n_in,
                              void* d_out, int out_size, void* d_ws, size_t ws_size,
                              hipStream_t stream) {
  const int B = 8, N = 8192, M = 2048;
  const float* pc = (const float*)d_in[0];
  const float* qc = (const float*)d_in[1];
  const float* temp = (const float*)d_in[2];
  float* out = (float*)d_out;

  size_t packBytes = (size_t)B * N * 16;  // B*N/2 pairs * 32B
  bool packed = (ws_size >= packBytes) && (d_ws != nullptr);

  int nblocks = (B * M) / 4;  // 4 queries / 256-thread block (1 per wave)
  if (packed) {
    int R = B * (N >> 1);
    prep_pack2<<<dim3((R + 255) / 256), dim3(256), 0, stream>>>(
        pc, (float4*)d_ws, B, N);
    knn9<true><<<dim3(nblocks), dim3(256), 0, stream>>>(
        pc, qc, temp, (const float4*)d_ws, out, B, N, M);
  } else {
    knn9<false><<<dim3(nblocks), dim3(256), 0, stream>>>(
        pc, qc, temp, nullptr, out, B, N, M);
  }
}

// Round 10
// 79.705 us; speedup vs baseline: 1.4242x; 1.0610x over previous
//
#include <hip/hip_runtime.h>
#include <stdint.h>

typedef unsigned long long u64;
typedef unsigned int u32;
typedef float f2 __attribute__((ext_vector_type(2)));

// ---- cross-lane helpers ----
__device__ __forceinline__ float dpp_shr1_f(float v, int fill_bits) {
  // within each 16-lane row: lane i <- lane i-1; row-lead takes fill
  return __int_as_float(__builtin_amdgcn_update_dpp(
      fill_bits, __float_as_int(v), 0x111 /*row_shr:1*/, 0xF, 0xF, false));
}
__device__ __forceinline__ int dpp_shr1_i(int v) {
  return __builtin_amdgcn_update_dpp(0, v, 0x111, 0xF, 0xF, false);
}
__device__ __forceinline__ float rdlane_f(float v, int lane) {
  return __int_as_float(__builtin_amdgcn_readlane(__float_as_int(v), lane));
}
// order-preserving float-bits -> u32 (monotone over all floats incl. negatives)
__device__ __forceinline__ u32 fkey(u32 s) {
  return s ^ ((u32)((int)s >> 31) | 0x80000000u);
}

// pair records for 128-pt chunks: pair (n0 = k*128+t, n1 = n0+64), t=0..63
// rec0 = {-2x0,-2x1,-2y0,-2y1}, rec1 = {-2z0,-2z1, pn0, pn1}
// x(-2) is exact so q*(-2p) == -2*inner bit-exactly; pn in numpy order.
__global__ void prep_pack2(const float* __restrict__ pc, float4* __restrict__ pp,
                           int B, int N) {
  int r = blockIdx.x * blockDim.x + threadIdx.x;  // pair id
  int H = N >> 1;
  if (r >= B * H) return;
  int b = r / H;
  int j = r - b * H;
  int k = j >> 6, t = j & 63;
  int n0 = (k << 7) + t, n1 = n0 + 64;
  const float* p = pc + (size_t)b * 3 * N;
  float x0 = p[n0], x1 = p[n1];
  float y0 = p[N + n0], y1 = p[N + n1];
  float z0 = p[2 * N + n0], z1 = p[2 * N + n1];
  float pn0 = __fadd_rn(__fadd_rn(__fmul_rn(x0, x0), __fmul_rn(y0, y0)),
                        __fmul_rn(z0, z0));
  float pn1 = __fadd_rn(__fadd_rn(__fmul_rn(x1, x1), __fmul_rn(y1, y1)),
                        __fmul_rn(z1, z1));
  pp[2 * r] = make_float4(__fmul_rn(x0, -2.0f), __fmul_rn(x1, -2.0f),
                          __fmul_rn(y0, -2.0f), __fmul_rn(y1, -2.0f));
  pp[2 * r + 1] = make_float4(__fmul_rn(z0, -2.0f), __fmul_rn(z1, -2.0f),
                              pn0, pn1);
}

struct Q4 { float4 a, b, c, d; };

template <bool PACKED>
__global__ __launch_bounds__(256, 8) void knn10(
    const float* __restrict__ pc,    // (B,3,N)
    const float* __restrict__ qc,    // (B,3,M)
    const float* __restrict__ temp,  // scalar
    const float4* __restrict__ pp,   // packed pair records
    float* __restrict__ out,         // (B,3,M)
    int B, int N, int M) {
#pragma clang fp contract(off)
  const float INF = __int_as_float(0x7f800000);
  const int NINF_BITS = (int)0xff800000;

  int tid = threadIdx.x;
  int lane = tid & 63;
  // force scalar: qid is wave-uniform -> b,q,base pointers live in SGPRs,
  // loads take the saddr+imm form with zero VALU address math.
  int qid = __builtin_amdgcn_readfirstlane(blockIdx.x * 4 + (tid >> 6));
  int b = qid >> 11;                      // M = 2048
  int q = qid & 2047;

  float qx = qc[(b * 3 + 0) * M + q];
  float qy = qc[(b * 3 + 1) * M + q];
  float qz = qc[(b * 3 + 2) * M + q];
  float qn = __fadd_rn(__fadd_rn(__fmul_rn(qx, qx), __fmul_rn(qy, qy)),
                       __fmul_rn(qz, qz));
  f2 qx2 = {qx, qx}, qy2 = {qy, qy}, qz2 = {qz, qz}, qn2 = {qn, qn};

  // distributed top-16: lane (l&15) holds entry (l&15), ascending; all four
  // 16-lane rows mirror the same list (updates are wave-uniform).
  float val = INF;
  int idx = 0;
  float thresh = INF;

  const float* __restrict__ pcb = pc + (size_t)b * 3 * N;

  // serial sorted-insert of candidates in mask (bit s <-> point g+s, ascending)
  auto ins = [&](u64 m, float dv, int g) {
    do {
      int s = __ffsll((long long)m) - 1;  // ascending idx = top_k tie-break
      m &= m - 1;
      float cv = rdlane_f(dv, s);         // wave-uniform candidate
      int ci = g + s;                     // SALU
      float pvv = dpp_shr1_f(val, NINF_BITS);
      int piv = dpp_shr1_i(idx);
      bool p = cv < val;                  // strict < keeps stability
      bool p2 = cv < pvv;
      float nv = __builtin_amdgcn_fmed3f(val, pvv, cv);  // sorted-insert step
      idx = p ? (p2 ? piv : ci) : idx;
      val = nv;
    } while (m);
  };

  auto dist = [&](float4 c0, float4 c1) -> f2 {
    // d2 = (qn+pn) + (qx*(-2px)+qy*(-2py)+qz*(-2pz)) == reference bit-exact
    f2 px = {c0.x, c0.y}, py = {c0.z, c0.w};
    f2 pz = {c1.x, c1.y}, pw = {c1.z, c1.w};
    f2 s1 = qx2 * px;
    f2 s2 = qy2 * py;
    f2 s3 = qz2 * pz;
    f2 t = (s1 + s2) + s3;
    return (qn2 + pw) + t;
  };

  if (PACKED) {
    // scalar base + per-lane constant byte offset; double-chunk = 256 pts =
    // 4 dwordx4/lane at imm offsets 0/16/2048/2064, stride 4096 B.
    const char* sbase = (const char*)(pp + (size_t)b * N);
    u32 vo = (u32)(lane << 5);
    auto LD = [&](int dc) {
      const char* p = sbase + ((size_t)dc << 12) + vo;
      Q4 r;
      r.a = *(const float4*)(p);
      r.b = *(const float4*)(p + 16);
      r.c = *(const float4*)(p + 2048);
      r.d = *(const float4*)(p + 2064);
      return r;
    };
    auto half = [&](float dv, int g) {
      u64 m = __ballot(dv < thresh);
      if (m) {
        ins(m, dv, g);
        thresh = rdlane_f(val, 15);
      }
    };
    auto proc = [&](const Q4& A, int g) {
      f2 dA = dist(A.a, A.b);
      f2 dB = dist(A.c, A.d);   // both up front for ILP
      half(dA.x, g);
      half(dA.y, g + 64);
      half(dB.x, g + 128);
      half(dB.y, g + 192);
    };

    Q4 A = LD(0), Bq = LD(1);
    {
      // ---- warmup on double-chunk 0: bitonic sort first 64 points ----
      f2 dA = dist(A.a, A.b);
      u64 key = ((u64)fkey(__float_as_uint(dA.x)) << 32) | (u32)lane;
#pragma unroll
      for (int k = 2; k <= 64; k <<= 1) {
#pragma unroll
        for (int j = k >> 1; j >= 1; j >>= 1) {
          u32 klo = (u32)key, khi = (u32)(key >> 32);
          u32 plo = (u32)__shfl_xor((int)klo, j);
          u32 phi = (u32)__shfl_xor((int)khi, j);
          u64 pkey = ((u64)phi << 32) | plo;
          bool keepMin = ((lane & j) == 0) == ((lane & k) == 0);
          bool lt = key < pkey;
          key = (lt == keepMin) ? key : pkey;
        }
      }
      {  // distribute sorted entries 0..15 to all four mirror rows
        int src = (lane & 15) << 2;
        u32 lo = (u32)__builtin_amdgcn_ds_bpermute(src, (int)(u32)key);
        u32 hi = (u32)__builtin_amdgcn_ds_bpermute(src, (int)(key >> 32));
        idx = (int)lo;
        val = __uint_as_float(hi ^ (((int)hi >= 0) ? 0xFFFFFFFFu : 0x80000000u));
        thresh = rdlane_f(val, 15);
      }
      half(dA.y, 64);
      f2 dB = dist(A.c, A.d);
      half(dB.x, 128);
      half(dB.y, 192);
    }
    A = LD(2);
    // ---- main loop: ping-pong, reload-in-place, no copies, no wrap ----
#pragma unroll 1
    for (int k = 1; k <= 27; k += 2) {
      proc(Bq, k << 8);
      Bq = LD(k + 2);
      proc(A, (k + 1) << 8);
      A = LD(k + 3);
    }
    proc(Bq, 29 << 8);
    Bq = LD(31);
    proc(A, 30 << 8);
    proc(Bq, 31 << 8);
  } else {
#pragma unroll 1
    for (int g = 0; g < N; g += 64) {
      int n = g + lane;
      float x = pcb[n], y = pcb[N + n], z = pcb[2 * N + n];
      float pn = __fadd_rn(__fadd_rn(__fmul_rn(x, x), __fmul_rn(y, y)),
                           __fmul_rn(z, z));
      float s1 = __fmul_rn(qx, __fmul_rn(x, -2.0f));
      float s2 = __fmul_rn(qy, __fmul_rn(y, -2.0f));
      float s3 = __fmul_rn(qz, __fmul_rn(z, -2.0f));
      float t = __fadd_rn(__fadd_rn(s1, s2), s3);
      float d2 = __fadd_rn(__fadd_rn(qn, pn), t);
      u64 m = __ballot(d2 < thresh);
      if (m) {
        ins(m, d2, g);
        thresh = rdlane_f(val, 15);
      }
    }
  }

  // ---- finisher (np-faithful): lane (l&15) owns entry (l&15) ----
  float Tv = temp[0];
  float sigma = fmaxf(__fmul_rn(Tv, Tv), 1e-4f);
  float sp = __fadd_rn(sigma, 1e-8f);
  int n = idx;
  float px = pcb[n], py = pcb[N + n], pz = pcb[2 * N + n];
  float dx = __fsub_rn(px, qx), dy = __fsub_rn(py, qy), dz = __fsub_rn(pz, qz);
  float d2w = __fadd_rn(__fadd_rn(__fmul_rn(dx, dx), __fmul_rn(dy, dy)),
                        __fmul_rn(dz, dz));
  float a = -__fdiv_rn(d2w, sp);   // -dist; softmax shift-invariant
  float m = rdlane_f(a, 0);        // entry 0 = nearest (sorted ascending)
  float e = expf(__fsub_rn(a, m));
  float Z = e;
#pragma unroll
  for (int d = 1; d < 16; d <<= 1) Z += __shfl_xor(Z, d, 16);
  float w = __fdiv_rn(e, Z);       // normalized weight
  float sx = __fmul_rn(px, w), sy = __fmul_rn(py, w), sz = __fmul_rn(pz, w);
#pragma unroll
  for (int d = 1; d < 16; d <<= 1) {
    sx += __shfl_xor(sx, d, 16);
    sy += __shfl_xor(sy, d, 16);
    sz += __shfl_xor(sz, d, 16);
  }
  if (lane < 3) {
    float r = (lane == 0) ? sx : ((lane == 1) ? sy : sz);
    out[(b * 3 + lane) * M + q] = r;
  }
}

extern "C" void kernel_launch(void* const* d_in, const int* in_sizes, int n_in,
                              void* d_out, int out_size, void* d_ws, size_t ws_size,
                              hipStream_t stream) {
  const int B = 8, N = 8192, M = 2048;
  const float* pc = (const float*)d_in[0];
  const float* qc = (const float*)d_in[1];
  const float* temp = (const float*)d_in[2];
  float* out = (float*)d_out;

  size_t packBytes = (size_t)B * N * 16;  // B*N/2 pairs * 32B
  bool packed = (ws_size >= packBytes) && (d_ws != nullptr);

  int nblocks = (B * M) / 4;  // 4 queries / 256-thread block (1 per wave)
  if (packed) {
    int R = B * (N >> 1);
    prep_pack2<<<dim3((R + 255) / 256), dim3(256), 0, stream>>>(
        pc, (float4*)d_ws, B, N);
    knn10<true><<<dim3(nblocks), dim3(256), 0, stream>>>(
        pc, qc, temp, (const float4*)d_ws, out, B, N, M);
  } else {
    knn10<false><<<dim3(nblocks), dim3(256), 0, stream>>>(
        pc, qc, temp, nullptr, out, B, N, M);
  }
}